// Round 14
// baseline (146.164 us; speedup 1.0000x reference)
//
#include <hip/hip_runtime.h>

#define NPIX 49152   // B*H*W = 1*192*256
#define H_ 192
#define W_ 256
#define TPB 64       // tokens per chain block (64 tokens x 4 lanes = 256 thr)

// ---------------------------------------------------------------------------
// both weight transposes (32 blocks) + zero binning counters (block 0)
// ---------------------------------------------------------------------------
__global__ __launch_bounds__(256) void wtrans2_k(const float* __restrict__ Wa,
    float* __restrict__ WTa, const float* __restrict__ Wb,
    float* __restrict__ WTb, int* __restrict__ S) {
  const int b = blockIdx.x;
  const float* __restrict__ W = (b < 16) ? Wa : Wb;
  float* __restrict__ WT = (b < 16) ? WTa : WTb;
  const int bb = b & 15;
  __shared__ float tile[32][33];
  const int bx = bb & 3, by = bb >> 2;
  const int c = threadIdx.x & 31, r0 = threadIdx.x >> 5;
#pragma unroll
  for (int j = 0; j < 4; ++j) {
    const int r = r0 + j * 8;
    tile[r][c] = W[(by * 32 + r) * 128 + bx * 32 + c];
  }
  __syncthreads();
#pragma unroll
  for (int j = 0; j < 4; ++j) {
    const int r = r0 + j * 8;
    WT[(bx * 32 + r) * 128 + by * 32 + c] = tile[c][r];
  }
  if (b == 0) {
    const int t = threadIdx.x;
    if (t < 32) S[t] = 0;        // cnt1 + cur1
    S[1088 + t] = 0;             // cnt2
    S[1344 + t] = 0;             // cur2
  }
}

// ---------------------------------------------------------------------------
// FUSED conv1 + conv2 + conv17 + argmax + mask + histogram + x transpose.
// 1024 threads = 16 waves; each wave owns 8 output channels x 64 pixels
// (lane = pixel). Weights on the scalar path with dwordx8 buffers (deeper
// prefetch than dwordx16 at same SGPR budget); 8 waves/SIMD residency.
// Per-output FMA chains (bias then k ascending) bitwise identical.
// ---------------------------------------------------------------------------
__global__ __launch_bounds__(1024) void convfused_k(
    const float* __restrict__ X,
    const float* __restrict__ WT1, const float* __restrict__ Bv1,
    const float* __restrict__ WT2, const float* __restrict__ Bv2,
    const float* __restrict__ W3, const float* __restrict__ Bv3,
    unsigned char* __restrict__ inds1, float* __restrict__ mask_out,
    int* __restrict__ cnt1, float* __restrict__ xt) {
  __shared__ float xs2[128][65];   // 33.3 KB raw x, then activations (pad 65)
  __shared__ float w3s[128 * 20];  // 10 KB W3 [k][20]
  __shared__ int lh[16];
  const int t = threadIdx.x;
  const int px = t & 63;           // lane = pixel within tile
  const int p0 = blockIdx.x * 64;
  int ob = (t >> 6) * 8;           // wave's 8-output base == its k-row base
  ob = __builtin_amdgcn_readfirstlane(ob);
  if (t < 16) lh[t] = 0;

  // ---- stage raw x: wave w loads k rows [ob, ob+8) for all 64 px ----
  {
    float xr[8];
#pragma unroll
    for (int kk = 0; kk < 8; ++kk)
      xr[kk] = X[(ob + kk) * NPIX + p0 + px];
#pragma unroll
    for (int kk = 0; kk < 8; ++kk)
      xs2[ob + kk][px] = xr[kk];
  }
  __syncthreads();

  float acc[8];

  // ================= PHASE 1: conv1 (x from LDS, W scalar) ===============
  const float* __restrict__ W1u = WT1 + ob;   // uniform base
#pragma unroll
  for (int o = 0; o < 8; ++o) acc[o] = Bv1[ob + o];
#pragma unroll 8
  for (int k = 0; k < 128; ++k) {
    const float xv = xs2[k][px];
#pragma unroll
    for (int o = 0; o < 8; ++o)
      acc[o] = fmaf(xv, W1u[k * 128 + o], acc[o]);
  }

  // ---- xt transpose write (coalesced row bursts from LDS cols) ----
#pragma unroll
  for (int i = 0; i < 2; ++i) {
    const int idx = t * 2 + i;
    const int tok = idx >> 5, c4 = idx & 31;   // token 0..63, f4-col 0..31
    const int pg = p0 + tok;
    float4 v;
    v.x = xs2[c4 * 4 + 0][tok];
    v.y = xs2[c4 * 4 + 1][tok];
    v.z = xs2[c4 * 4 + 2][tok];
    v.w = xs2[c4 * 4 + 3][tok];
    *(float4*)(xt + ((pg & 255) * H_ + (pg >> 8)) * 128 + c4 * 4) = v;
  }
  __syncthreads();   // xt LDS reads + phase-1 reads done before overwrite

  // epilogue 1: lrelu -> xs2 (activations)
#pragma unroll
  for (int o = 0; o < 8; ++o) {
    const float v = acc[o];
    xs2[ob + o][px] = v > 0.f ? v : 0.01f * v;
  }
  __syncthreads();

  // ================= PHASE 2: conv2 (x from LDS, W scalar) ===============
  const float* __restrict__ W2u = WT2 + ob;
#pragma unroll
  for (int o = 0; o < 8; ++o) acc[o] = Bv2[ob + o];
#pragma unroll 8
  for (int k = 0; k < 128; ++k) {
    const float xv = xs2[k][px];
#pragma unroll
    for (int o = 0; o < 8; ++o)
      acc[o] = fmaf(xv, W2u[k * 128 + o], acc[o]);
  }
  __syncthreads();   // all phase-2 reads of xs2 complete

  // epilogue 2: lrelu -> xs2 ; stage W3 as w3s[k][20]
#pragma unroll
  for (int o = 0; o < 8; ++o) {
    const float v = acc[o];
    xs2[ob + o][px] = v > 0.f ? v : 0.01f * v;
  }
  for (int i = t; i < 17 * 128; i += 1024)
    w3s[(i & 127) * 20 + (i >> 7)] = W3[i];
  __syncthreads();

  // ===== PHASE 3: conv17 + argmax + mask + hist (16 lanes per pixel) ====
  {
    const int p = t >> 4, s = t & 15;     // pixel 0..63, logit owner 0..15
    float s1 = Bv3[s];
    float m = Bv3[16];
#pragma unroll 8
    for (int k = 0; k < 128; ++k) {
      const float xv = xs2[k][p];
      s1 = fmaf(xv, w3s[k * 20 + s], s1);
      m = fmaf(xv, w3s[k * 20 + 16], m);
    }
    // argmax over 16: lane owns logit s; min-index-of-max combine across
    // the 16-lane group (== serial first-max-wins)
    float bv = s1;
    int bi = s;
#pragma unroll
    for (int d = 1; d < 16; d <<= 1) {
      const float ov = __shfl_xor(bv, d, 64);
      const int oi = __shfl_xor(bi, d, 64);
      if (ov > bv || (ov == bv && oi < bi)) { bv = ov; bi = oi; }
    }
    if (s == 0) {
      inds1[p0 + p] = (unsigned char)bi;
      mask_out[p0 + p] = m > 0.f ? m : 0.01f * m;
      atomicAdd(&lh[bi], 1);
    }
  }
  __syncthreads();
  if (t < 16 && lh[t] > 0) atomicAdd(&cnt1[t], lh[t]);
}

// parallel scan + descriptor emit
template<int NB>
__global__ __launch_bounds__(256) void scan_desc_k(const int* __restrict__ cnt,
    int* __restrict__ off, int* __restrict__ desc, int* __restrict__ ndesc) {
  const int t = threadIdx.x;
  const int lane = t & 63, wvi = t >> 6;
  __shared__ int wsumC[4], wsumD[4];
  const int c = (t < NB) ? cnt[t] : 0;
  const int nb = (c + TPB - 1) / TPB;
  int ic = c, id = nb;
  for (int d = 1; d < 64; d <<= 1) {
    const int uc = __shfl_up(ic, d, 64);
    const int ud = __shfl_up(id, d, 64);
    if (lane >= d) { ic += uc; id += ud; }
  }
  if (lane == 63) { wsumC[wvi] = ic; wsumD[wvi] = id; }
  __syncthreads();
  int bc = 0, bd = 0;
#pragma unroll
  for (int w2 = 0; w2 < 4; ++w2) {
    if (w2 < wvi) { bc += wsumC[w2]; bd += wsumD[w2]; }
  }
  ic += bc; id += bd;
  if (t < NB) {
    off[t] = ic - c;
    const int db = id - nb;
    for (int j = 0; j < nb; ++j) desc[db + j] = (t << 12) | j;
  }
  if (t == NB - 1) *ndesc = id;
}

// two-level scatter
template<typename T>
__global__ __launch_bounds__(256) void scatter_k(const T* __restrict__ bins,
    const int* __restrict__ off, int* __restrict__ cursor,
    int* __restrict__ ord, int nbins) {
  __shared__ int lhist[256], lbase[256], lcur[256];
  const int t = threadIdx.x;
  const int n = blockIdx.x * 256 + t;
  if (t < nbins) { lhist[t] = 0; lcur[t] = 0; }
  __syncthreads();
  const int b = (int)bins[n];
  atomicAdd(&lhist[b], 1);
  __syncthreads();
  if (t < nbins && lhist[t] > 0) lbase[t] = atomicAdd(&cursor[t], lhist[t]);
  __syncthreads();
  const int r = atomicAdd(&lcur[b], 1);
  ord[off[b] + lbase[b] + r] = n;
}

// ---------------------------------------------------------------------------
// chain1 v5 (unchanged): LDS-staged expert weights + x rows; pure-LDS k-loop.
// ---------------------------------------------------------------------------
__global__ __launch_bounds__(256) void chain1_k(const float* __restrict__ xt,
    const int* __restrict__ ord1, const int* __restrict__ off1,
    const int* __restrict__ cnt1, const int* __restrict__ desc1,
    const int* __restrict__ nd1,
    const float* __restrict__ wc21, const float* __restrict__ bc21,
    const float* __restrict__ wc22, const float* __restrict__ bc22,
    const float* __restrict__ wc23, const float* __restrict__ bc23,
    int* __restrict__ e12a, int* __restrict__ cnt2) {
  if ((int)blockIdx.x >= *nd1) return;
  __shared__ float w1s[4096];
  __shared__ float w2s[1024];
  __shared__ float w3s[512];
  __shared__ float bs[80];
  __shared__ float xs_[64][132];
  __shared__ int lh[16];
  const int t = threadIdx.x;
  if (t < 16) lh[t] = 0;
  const int tg = t >> 2, sub = t & 3;
  const int l0 = (t & 63) & ~3;
  const int de = desc1[blockIdx.x];
  const int e = de >> 12, chunk = de & 0xFFF;
  const int cnt = cnt1[e];
  const int pos = chunk * TPB + tg;
  const bool valid = pos < cnt;
  const int n = valid ? ord1[off1[e] + pos] : 0;

  {
    const float4* __restrict__ Wg1 = (const float4*)(wc21 + e * 4096);
#pragma unroll
    for (int j = 0; j < 4; ++j)
      *(float4*)&w1s[t * 4 + j * 1024] = Wg1[t + j * 256];
    const float4* __restrict__ Wg2 = (const float4*)(wc22 + e * 1024);
    *(float4*)&w2s[t * 4] = Wg2[t];
    if (t < 128) {
      const float4* __restrict__ Wg3 = (const float4*)(wc23 + e * 512);
      *(float4*)&w3s[t * 4] = Wg3[t];
    }
    if (t < 32) bs[t] = bc21[e * 32 + t];
    else if (t < 64) bs[t] = bc22[e * 32 + (t - 32)];
    else if (t < 80) bs[t] = bc23[e * 16 + (t - 64)];
  }
  {
    const float4* __restrict__ src = (const float4*)(xt + n * 128 + sub * 32);
    float4 tmp[8];
#pragma unroll
    for (int j = 0; j < 8; ++j) tmp[j] = src[j];
#pragma unroll
    for (int j = 0; j < 8; ++j)
      *(float4*)(&xs_[tg][sub * 32 + 4 * j]) = tmp[j];
  }
  __syncthreads();

  const int wb1 = sub * 8;
  float a[8];
#pragma unroll
  for (int o = 0; o < 8; ++o) a[o] = bs[wb1 + o];
#pragma unroll
  for (int k = 0; k < 128; k += 4) {
    float x4[4];
    *(float4*)x4 = *(const float4*)(&xs_[tg][k]);
#pragma unroll
    for (int kk = 0; kk < 4; ++kk) {
      float w8[8];
      *(float4*)&w8[0] = *(const float4*)&w1s[(k + kk) * 32 + wb1];
      *(float4*)&w8[4] = *(const float4*)&w1s[(k + kk) * 32 + wb1 + 4];
#pragma unroll
      for (int o = 0; o < 8; ++o) a[o] = fmaf(x4[kk], w8[o], a[o]);
    }
  }
#pragma unroll
  for (int o = 0; o < 8; ++o) a[o] = a[o] > 0.f ? a[o] : 0.01f * a[o];

  float b[8];
#pragma unroll
  for (int o = 0; o < 8; ++o) b[o] = bs[32 + wb1 + o];
#pragma unroll
  for (int i = 0; i < 32; ++i) {
    const float hv = __shfl(a[i & 7], l0 + (i >> 3), 64);
    float w8[8];
    *(float4*)&w8[0] = *(const float4*)&w2s[i * 32 + wb1];
    *(float4*)&w8[4] = *(const float4*)&w2s[i * 32 + wb1 + 4];
#pragma unroll
    for (int o = 0; o < 8; ++o) b[o] = fmaf(hv, w8[o], b[o]);
  }
#pragma unroll
  for (int o = 0; o < 8; ++o) b[o] = b[o] > 0.f ? b[o] : 0.01f * b[o];

  float s[4];
#pragma unroll
  for (int j = 0; j < 4; ++j) s[j] = bs[64 + sub * 4 + j];
#pragma unroll
  for (int i = 0; i < 32; ++i) {
    const float hv = __shfl(b[i & 7], l0 + (i >> 3), 64);
    float w4[4];
    *(float4*)w4 = *(const float4*)&w3s[i * 16 + sub * 4];
#pragma unroll
    for (int j = 0; j < 4; ++j) s[j] = fmaf(hv, w4[j], s[j]);
  }

  float bv = s[0];
  int bi = sub * 4;
#pragma unroll
  for (int j = 1; j < 4; ++j) {
    if (s[j] > bv) { bv = s[j]; bi = sub * 4 + j; }
  }
#pragma unroll
  for (int d = 1; d < 4; d <<= 1) {
    const float ov = __shfl_xor(bv, d, 64);
    const int oi = __shfl_xor(bi, d, 64);
    if (ov > bv || (ov == bv && oi < bi)) { bv = ov; bi = oi; }
  }
  const int e12 = e * 16 + bi;
  if (valid && sub == 0) {
    e12a[n] = e12;
    atomicAdd(&lh[bi], 1);
  }
  __syncthreads();
  if (t < 16 && lh[t] > 0)
    atomicAdd(&cnt2[e * 16 + t], lh[t]);
}

// ---------------------------------------------------------------------------
// chain2 v5 (unchanged): LDS-weight-staged. Writes out[n].
// ---------------------------------------------------------------------------
__global__ __launch_bounds__(256) void chain2_k(const float* __restrict__ xt,
    const int* __restrict__ ord2, const int* __restrict__ off2,
    const int* __restrict__ cnt2, const int* __restrict__ desc2,
    const int* __restrict__ nd2,
    const float* __restrict__ wr11, const float* __restrict__ br11,
    const float* __restrict__ wr12, const float* __restrict__ br12,
    const float* __restrict__ wr13, const float* __restrict__ br13,
    float* __restrict__ out) {
  if ((int)blockIdx.x >= *nd2) return;
  __shared__ float w1s[4096];
  __shared__ float w2s[512];
  __shared__ float w3s[16];
  __shared__ float bs[49];
  __shared__ float xs_[64][132];
  const int t = threadIdx.x;
  const int tg = t >> 2, sub = t & 3;
  const int l0 = (t & 63) & ~3;
  const int de = desc2[blockIdx.x];
  const int e12 = de >> 12, chunk = de & 0xFFF;
  const int cnt = cnt2[e12];
  const int pos = chunk * TPB + tg;
  const bool valid = pos < cnt;
  const int n = valid ? ord2[off2[e12] + pos] : 0;

  {
    const float4* __restrict__ Wg1 = (const float4*)(wr11 + e12 * 4096);
#pragma unroll
    for (int j = 0; j < 4; ++j)
      *(float4*)&w1s[t * 4 + j * 1024] = Wg1[t + j * 256];
    if (t < 128) {
      const float4* __restrict__ Wg2 = (const float4*)(wr12 + e12 * 512);
      *(float4*)&w2s[t * 4] = Wg2[t];
    }
    if (t < 16) w3s[t] = wr13[e12 * 16 + t];
    if (t < 32) bs[t] = br11[e12 * 32 + t];
    else if (t < 48) bs[t] = br12[e12 * 16 + (t - 32)];
    else if (t == 48) bs[48] = br13[e12];
  }
  {
    const float4* __restrict__ src = (const float4*)(xt + n * 128 + sub * 32);
    float4 tmp[8];
#pragma unroll
    for (int j = 0; j < 8; ++j) tmp[j] = src[j];
#pragma unroll
    for (int j = 0; j < 8; ++j)
      *(float4*)(&xs_[tg][sub * 32 + 4 * j]) = tmp[j];
  }
  __syncthreads();

  const int wb1 = sub * 8;
  float a[8];
#pragma unroll
  for (int o = 0; o < 8; ++o) a[o] = bs[wb1 + o];
#pragma unroll
  for (int k = 0; k < 128; k += 4) {
    float x4[4];
    *(float4*)x4 = *(const float4*)(&xs_[tg][k]);
#pragma unroll
    for (int kk = 0; kk < 4; ++kk) {
      float w8[8];
      *(float4*)&w8[0] = *(const float4*)&w1s[(k + kk) * 32 + wb1];
      *(float4*)&w8[4] = *(const float4*)&w1s[(k + kk) * 32 + wb1 + 4];
#pragma unroll
      for (int o = 0; o < 8; ++o) a[o] = fmaf(x4[kk], w8[o], a[o]);
    }
  }
#pragma unroll
  for (int o = 0; o < 8; ++o) a[o] = a[o] > 0.f ? a[o] : 0.01f * a[o];

  float s[4];
#pragma unroll
  for (int j = 0; j < 4; ++j) s[j] = bs[32 + sub * 4 + j];
#pragma unroll
  for (int i = 0; i < 32; ++i) {
    const float hv = __shfl(a[i & 7], l0 + (i >> 3), 64);
    float w4[4];
    *(float4*)w4 = *(const float4*)&w2s[i * 16 + sub * 4];
#pragma unroll
    for (int j = 0; j < 4; ++j) s[j] = fmaf(hv, w4[j], s[j]);
  }
#pragma unroll
  for (int j = 0; j < 4; ++j) s[j] = s[j] > 0.f ? s[j] : 0.01f * s[j];

  float r = bs[48];
#pragma unroll
  for (int i = 0; i < 16; ++i) {
    const float hv = __shfl(s[i & 3], l0 + (i >> 2), 64);
    r = fmaf(hv, w3s[i], r);
  }

  if (valid && sub == 0) out[n] = ((float)e12 + r) * (1.0f / 256.0f);
}

// ---------------------------------------------------------------------------
extern "C" void kernel_launch(void* const* d_in, const int* in_sizes, int n_in,
                              void* d_out, int out_size, void* d_ws,
                              size_t ws_size, hipStream_t stream) {
  const float* x_in  = (const float*)d_in[0];
  const float* w_c11 = (const float*)d_in[1];
  const float* b_c11 = (const float*)d_in[2];
  const float* w_c12 = (const float*)d_in[3];
  const float* b_c12 = (const float*)d_in[4];
  const float* w_c13 = (const float*)d_in[5];
  const float* b_c13 = (const float*)d_in[6];
  const float* w_c21 = (const float*)d_in[7];
  const float* b_c21 = (const float*)d_in[8];
  const float* w_c22 = (const float*)d_in[9];
  const float* b_c22 = (const float*)d_in[10];
  const float* w_c23 = (const float*)d_in[11];
  const float* b_c23 = (const float*)d_in[12];
  const float* w_r11 = (const float*)d_in[13];
  const float* b_r11 = (const float*)d_in[14];
  const float* w_r12 = (const float*)d_in[15];
  const float* b_r12 = (const float*)d_in[16];
  const float* w_r13 = (const float*)d_in[17];
  const float* b_r13 = (const float*)d_in[18];

  float* out = (float*)d_out;   // [0..N): x_real (token order), [N..2N): mask

  float* R0 = (float*)d_ws;
  float* R1 = R0 + 128 * NPIX;
  float* R2 = R1 + 128 * NPIX;

  float* xt = R0;
  unsigned char* inds1 = (unsigned char*)R2;   // N bytes
  float* wT1 = R2 + 12288;
  float* wT2 = wT1 + 16384;
  int* S = (int*)R2 + 45056;

  int* cnt1  = S;            // 16
  int* cur1  = S + 16;       // 16
  int* off1  = S + 32;       // 16
  int* nd1   = S + 48;       // 1 (+pad)
  int* desc1 = S + 64;       // 1024
  int* cnt2  = S + 1088;     // 256
  int* cur2  = S + 1344;     // 256
  int* off2  = S + 1600;     // 256
  int* nd2   = S + 1856;     // 1 (+pad)
  int* desc2 = S + 1872;     // 1024

  int* ib   = (int*)R1;
  int* ord1 = ib;            // N
  int* ord2 = ib + NPIX;     // N
  int* e12a = ib + 2 * NPIX; // N

  wtrans2_k<<<32, 256, 0, stream>>>(w_c11, wT1, w_c12, wT2, S);
  convfused_k<<<NPIX / 64, 1024, 0, stream>>>(x_in, wT1, b_c11, wT2, b_c12,
      w_c13, b_c13, inds1, out + NPIX, cnt1, xt);
  scan_desc_k<16><<<1, 256, 0, stream>>>(cnt1, off1, desc1, nd1);
  scatter_k<unsigned char><<<NPIX / 256, 256, 0, stream>>>(inds1, off1, cur1,
                                                           ord1, 16);
  chain1_k<<<NPIX / TPB + 16, 256, 0, stream>>>(xt, ord1, off1, cnt1, desc1,
      nd1, w_c21, b_c21, w_c22, b_c22, w_c23, b_c23, e12a, cnt2);
  scan_desc_k<256><<<1, 256, 0, stream>>>(cnt2, off2, desc2, nd2);
  scatter_k<int><<<NPIX / 256, 256, 0, stream>>>(e12a, off2, cur2, ord2, 256);
  chain2_k<<<NPIX / TPB + 256, 256, 0, stream>>>(xt, ord2, off2, cnt2, desc2,
      nd2, w_r11, b_r11, w_r12, b_r12, w_r13, b_r13, out);
}

// Round 15
// 144.398 us; speedup vs baseline: 1.0122x; 1.0122x over previous
//
#include <hip/hip_runtime.h>

#define NPIX 49152   // B*H*W = 1*192*256
#define H_ 192
#define W_ 256
#define TPB 64       // tokens per chain block (64 tokens; 256 thr = 4 waves)

// ---------------------------------------------------------------------------
// both weight transposes (32 blocks) + zero binning counters (block 0)
// ---------------------------------------------------------------------------
__global__ __launch_bounds__(256) void wtrans2_k(const float* __restrict__ Wa,
    float* __restrict__ WTa, const float* __restrict__ Wb,
    float* __restrict__ WTb, int* __restrict__ S) {
  const int b = blockIdx.x;
  const float* __restrict__ W = (b < 16) ? Wa : Wb;
  float* __restrict__ WT = (b < 16) ? WTa : WTb;
  const int bb = b & 15;
  __shared__ float tile[32][33];
  const int bx = bb & 3, by = bb >> 2;
  const int c = threadIdx.x & 31, r0 = threadIdx.x >> 5;
#pragma unroll
  for (int j = 0; j < 4; ++j) {
    const int r = r0 + j * 8;
    tile[r][c] = W[(by * 32 + r) * 128 + bx * 32 + c];
  }
  __syncthreads();
#pragma unroll
  for (int j = 0; j < 4; ++j) {
    const int r = r0 + j * 8;
    WT[(bx * 32 + r) * 128 + by * 32 + c] = tile[c][r];
  }
  if (b == 0) {
    const int t = threadIdx.x;
    if (t < 32) S[t] = 0;        // cnt1 + cur1
    S[1088 + t] = 0;             // cnt2
    S[1344 + t] = 0;             // cur2
  }
}

// ---------------------------------------------------------------------------
// FUSED conv1 + conv2 + conv17 + argmax + mask + histogram + x transpose.
// (round-13 version, proven 58 µs: 512 thr, 16 outputs/wave, scalar weights)
// ---------------------------------------------------------------------------
__global__ __launch_bounds__(512) void convfused_k(const float* __restrict__ X,
    const float* __restrict__ WT1, const float* __restrict__ Bv1,
    const float* __restrict__ WT2, const float* __restrict__ Bv2,
    const float* __restrict__ W3, const float* __restrict__ Bv3,
    unsigned char* __restrict__ inds1, float* __restrict__ mask_out,
    int* __restrict__ cnt1, float* __restrict__ xt) {
  __shared__ float xs2[128][65];   // 33.3 KB raw x, then activations (pad 65)
  __shared__ float w3s[128 * 20];  // 10 KB W3 [k][20]
  __shared__ int lh[16];
  const int t = threadIdx.x;
  const int px = t & 63;           // lane = pixel within tile
  const int p0 = blockIdx.x * 64;
  int ob = (t >> 6) * 16;          // wave's 16-output base == its k-row base
  ob = __builtin_amdgcn_readfirstlane(ob);
  if (t < 16) lh[t] = 0;

  // ---- stage raw x: wave w loads k rows [ob, ob+16) for all 64 px ----
  {
    float xr[16];
#pragma unroll
    for (int kk = 0; kk < 16; ++kk)
      xr[kk] = X[(ob + kk) * NPIX + p0 + px];
#pragma unroll
    for (int kk = 0; kk < 16; ++kk)
      xs2[ob + kk][px] = xr[kk];
  }
  __syncthreads();

  float acc[16];

  // ================= PHASE 1: conv1 (x from LDS, W scalar) ===============
  const float* __restrict__ W1u = WT1 + ob;   // uniform base
#pragma unroll
  for (int o = 0; o < 16; ++o) acc[o] = Bv1[ob + o];
#pragma unroll 8
  for (int k = 0; k < 128; ++k) {
    const float xv = xs2[k][px];
#pragma unroll
    for (int o = 0; o < 16; ++o)
      acc[o] = fmaf(xv, W1u[k * 128 + o], acc[o]);
  }

  // ---- xt transpose write (coalesced row bursts from LDS cols) ----
#pragma unroll
  for (int i = 0; i < 4; ++i) {
    const int idx = t * 4 + i;
    const int tok = idx >> 5, c4 = idx & 31;   // token 0..63, f4-col 0..31
    const int pg = p0 + tok;
    float4 v;
    v.x = xs2[c4 * 4 + 0][tok];
    v.y = xs2[c4 * 4 + 1][tok];
    v.z = xs2[c4 * 4 + 2][tok];
    v.w = xs2[c4 * 4 + 3][tok];
    *(float4*)(xt + ((pg & 255) * H_ + (pg >> 8)) * 128 + c4 * 4) = v;
  }
  __syncthreads();   // xt LDS reads + phase-1 reads done before overwrite

  // epilogue 1: lrelu -> xs2 (activations)
#pragma unroll
  for (int o = 0; o < 16; ++o) {
    const float v = acc[o];
    xs2[ob + o][px] = v > 0.f ? v : 0.01f * v;
  }
  __syncthreads();

  // ================= PHASE 2: conv2 (x from LDS, W scalar) ===============
  const float* __restrict__ W2u = WT2 + ob;
#pragma unroll
  for (int o = 0; o < 16; ++o) acc[o] = Bv2[ob + o];
#pragma unroll 8
  for (int k = 0; k < 128; ++k) {
    const float xv = xs2[k][px];
#pragma unroll
    for (int o = 0; o < 16; ++o)
      acc[o] = fmaf(xv, W2u[k * 128 + o], acc[o]);
  }
  __syncthreads();   // all phase-2 reads of xs2 complete

  // epilogue 2: lrelu -> xs2 ; stage W3 as w3s[k][20]
#pragma unroll
  for (int o = 0; o < 16; ++o) {
    const float v = acc[o];
    xs2[ob + o][px] = v > 0.f ? v : 0.01f * v;
  }
  for (int i = t; i < 17 * 128; i += 512)
    w3s[(i & 127) * 20 + (i >> 7)] = W3[i];
  __syncthreads();

  // ===== PHASE 3: conv17 + argmax + mask + hist (8 lanes per pixel) =====
  {
    const int p = t >> 3, s = t & 7;      // pixel 0..63, logit-pair owner
    float s2[2];
    s2[0] = Bv3[2 * s];
    s2[1] = Bv3[2 * s + 1];
    float m = Bv3[16];
#pragma unroll 8
    for (int k = 0; k < 128; ++k) {
      const float xv = xs2[k][p];
      float2 w2 = *(const float2*)&w3s[k * 20 + 2 * s];
      s2[0] = fmaf(xv, w2.x, s2[0]);
      s2[1] = fmaf(xv, w2.y, s2[1]);
      m = fmaf(xv, w3s[k * 20 + 16], m);
    }
    // argmax over 16: local first-max-wins over {2s,2s+1}, then
    // min-index-of-max combine across the 8-lane group
    float bv = s2[0];
    int bi = 2 * s;
    if (s2[1] > bv) { bv = s2[1]; bi = 2 * s + 1; }
#pragma unroll
    for (int d = 1; d < 8; d <<= 1) {
      const float ov = __shfl_xor(bv, d, 64);
      const int oi = __shfl_xor(bi, d, 64);
      if (ov > bv || (ov == bv && oi < bi)) { bv = ov; bi = oi; }
    }
    if (s == 0) {
      inds1[p0 + p] = (unsigned char)bi;
      mask_out[p0 + p] = m > 0.f ? m : 0.01f * m;
      atomicAdd(&lh[bi], 1);
    }
  }
  __syncthreads();
  if (t < 16 && lh[t] > 0) atomicAdd(&cnt1[t], lh[t]);
}

// parallel scan + descriptor emit
template<int NB>
__global__ __launch_bounds__(256) void scan_desc_k(const int* __restrict__ cnt,
    int* __restrict__ off, int* __restrict__ desc, int* __restrict__ ndesc) {
  const int t = threadIdx.x;
  const int lane = t & 63, wvi = t >> 6;
  __shared__ int wsumC[4], wsumD[4];
  const int c = (t < NB) ? cnt[t] : 0;
  const int nb = (c + TPB - 1) / TPB;
  int ic = c, id = nb;
  for (int d = 1; d < 64; d <<= 1) {
    const int uc = __shfl_up(ic, d, 64);
    const int ud = __shfl_up(id, d, 64);
    if (lane >= d) { ic += uc; id += ud; }
  }
  if (lane == 63) { wsumC[wvi] = ic; wsumD[wvi] = id; }
  __syncthreads();
  int bc = 0, bd = 0;
#pragma unroll
  for (int w2 = 0; w2 < 4; ++w2) {
    if (w2 < wvi) { bc += wsumC[w2]; bd += wsumD[w2]; }
  }
  ic += bc; id += bd;
  if (t < NB) {
    off[t] = ic - c;
    const int db = id - nb;
    for (int j = 0; j < nb; ++j) desc[db + j] = (t << 12) | j;
  }
  if (t == NB - 1) *ndesc = id;
}

// two-level scatter
template<typename T>
__global__ __launch_bounds__(256) void scatter_k(const T* __restrict__ bins,
    const int* __restrict__ off, int* __restrict__ cursor,
    int* __restrict__ ord, int nbins) {
  __shared__ int lhist[256], lbase[256], lcur[256];
  const int t = threadIdx.x;
  const int n = blockIdx.x * 256 + t;
  if (t < nbins) { lhist[t] = 0; lcur[t] = 0; }
  __syncthreads();
  const int b = (int)bins[n];
  atomicAdd(&lhist[b], 1);
  __syncthreads();
  if (t < nbins && lhist[t] > 0) lbase[t] = atomicAdd(&cursor[t], lhist[t]);
  __syncthreads();
  const int r = atomicAdd(&lcur[b], 1);
  ord[off[b] + lbase[b] + r] = n;
}

// ---------------------------------------------------------------------------
// chain1 v6: lane = token (64 tokens/block), wave = output slice. Weights on
// the scalar path straight from global (wave-uniform addresses, no staging);
// x and inter-layer activations in LDS with conflict-free [feat][tok] layout.
// Accumulation per output: bias then k/i ascending — bitwise identical to v5.
// Argmax: original serial first-max-wins over the 16 logits.
// ---------------------------------------------------------------------------
__global__ __launch_bounds__(256) void chain1_k(const float* __restrict__ xt,
    const int* __restrict__ ord1, const int* __restrict__ off1,
    const int* __restrict__ cnt1, const int* __restrict__ desc1,
    const int* __restrict__ nd1,
    const float* __restrict__ wc21, const float* __restrict__ bc21,
    const float* __restrict__ wc22, const float* __restrict__ bc22,
    const float* __restrict__ wc23, const float* __restrict__ bc23,
    int* __restrict__ e12a, int* __restrict__ cnt2) {
  if ((int)blockIdx.x >= *nd1) return;
  __shared__ float xs_t[128][65];   // [k][tok] 33.3 KB
  __shared__ float actA[32][65];    // L1 out, later logits
  __shared__ float actB[32][65];    // L2 out
  __shared__ int lh[16];
  const int t = threadIdx.x;
  if (t < 16) lh[t] = 0;
  const int tok = t & 63;
  int w = t >> 6;                   // wave id 0..3 (wave-uniform)
  w = __builtin_amdgcn_readfirstlane(w);
  const int de = desc1[blockIdx.x];
  const int e = de >> 12, chunk = de & 0xFFF;
  const int cnt = cnt1[e];
  const int pos = chunk * TPB + tok;
  const bool valid = pos < cnt;
  const int n = valid ? ord1[off1[e] + pos] : 0;

  // stage: thread (w,tok) loads k-quarter [w*32, w*32+32) of its token
  {
    const float4* __restrict__ src = (const float4*)(xt + n * 128 + w * 32);
    float4 tmp[8];
#pragma unroll
    for (int j = 0; j < 8; ++j) tmp[j] = src[j];
#pragma unroll
    for (int j = 0; j < 8; ++j) {
      const float* v = (const float*)&tmp[j];
#pragma unroll
      for (int c = 0; c < 4; ++c)
        xs_t[w * 32 + j * 4 + c][tok] = v[c];
    }
  }
  __syncthreads();

  // L1: 128 -> 32; wave w owns outputs w*8 .. w*8+7 (W scalar from global)
  const float* __restrict__ W1u = wc21 + e * 4096 + w * 8;
  const float* __restrict__ B1u = bc21 + e * 32 + w * 8;
  float a[8];
#pragma unroll
  for (int o = 0; o < 8; ++o) a[o] = B1u[o];
#pragma unroll 8
  for (int k = 0; k < 128; ++k) {
    const float xv = xs_t[k][tok];
#pragma unroll
    for (int o = 0; o < 8; ++o)
      a[o] = fmaf(xv, W1u[k * 32 + o], a[o]);
  }
#pragma unroll
  for (int o = 0; o < 8; ++o) {
    const float v = a[o] > 0.f ? a[o] : 0.01f * a[o];
    actA[w * 8 + o][tok] = v;
  }
  __syncthreads();

  // L2: 32 -> 32; wave w owns outputs w*8 .. w*8+7
  const float* __restrict__ W2u = wc22 + e * 1024 + w * 8;
  const float* __restrict__ B2u = bc22 + e * 32 + w * 8;
  float b[8];
#pragma unroll
  for (int o = 0; o < 8; ++o) b[o] = B2u[o];
#pragma unroll 8
  for (int i = 0; i < 32; ++i) {
    const float hv = actA[i][tok];
#pragma unroll
    for (int o = 0; o < 8; ++o)
      b[o] = fmaf(hv, W2u[i * 32 + o], b[o]);
  }
#pragma unroll
  for (int o = 0; o < 8; ++o) {
    const float v = b[o] > 0.f ? b[o] : 0.01f * b[o];
    actB[w * 8 + o][tok] = v;
  }
  __syncthreads();   // actB visible; all actA reads done

  // L3: 32 -> 16; wave w owns outputs w*4 .. w*4+3 ; logits into actA
  const float* __restrict__ W3u = wc23 + e * 512 + w * 4;
  const float* __restrict__ B3u = bc23 + e * 16 + w * 4;
  float s[4];
#pragma unroll
  for (int j = 0; j < 4; ++j) s[j] = B3u[j];
#pragma unroll 8
  for (int i = 0; i < 32; ++i) {
    const float hv = actB[i][tok];
#pragma unroll
    for (int j = 0; j < 4; ++j)
      s[j] = fmaf(hv, W3u[i * 16 + j], s[j]);
  }
#pragma unroll
  for (int j = 0; j < 4; ++j) actA[w * 4 + j][tok] = s[j];
  __syncthreads();

  // argmax (serial first-max-wins, original semantics) + histogram
  if (t < 64) {
    float bv = actA[0][tok];
    int am = 0;
#pragma unroll
    for (int o = 1; o < 16; ++o) {
      const float v = actA[o][tok];
      if (v > bv) { bv = v; am = o; }
    }
    if (valid) {
      e12a[n] = e * 16 + am;
      atomicAdd(&lh[am], 1);
    }
  }
  __syncthreads();
  if (t < 16 && lh[t] > 0)
    atomicAdd(&cnt2[e * 16 + t], lh[t]);
}

// ---------------------------------------------------------------------------
// chain2 v6: same lane=token / scalar-weight structure. Writes out[n].
// ---------------------------------------------------------------------------
__global__ __launch_bounds__(256) void chain2_k(const float* __restrict__ xt,
    const int* __restrict__ ord2, const int* __restrict__ off2,
    const int* __restrict__ cnt2, const int* __restrict__ desc2,
    const int* __restrict__ nd2,
    const float* __restrict__ wr11, const float* __restrict__ br11,
    const float* __restrict__ wr12, const float* __restrict__ br12,
    const float* __restrict__ wr13, const float* __restrict__ br13,
    float* __restrict__ out) {
  if ((int)blockIdx.x >= *nd2) return;
  __shared__ float xs_t[128][65];
  __shared__ float actA[32][65];
  __shared__ float actB[16][65];
  const int t = threadIdx.x;
  const int tok = t & 63;
  int w = t >> 6;
  w = __builtin_amdgcn_readfirstlane(w);
  const int de = desc2[blockIdx.x];
  const int e12 = de >> 12, chunk = de & 0xFFF;
  const int cnt = cnt2[e12];
  const int pos = chunk * TPB + tok;
  const bool valid = pos < cnt;
  const int n = valid ? ord2[off2[e12] + pos] : 0;

  {
    const float4* __restrict__ src = (const float4*)(xt + n * 128 + w * 32);
    float4 tmp[8];
#pragma unroll
    for (int j = 0; j < 8; ++j) tmp[j] = src[j];
#pragma unroll
    for (int j = 0; j < 8; ++j) {
      const float* v = (const float*)&tmp[j];
#pragma unroll
      for (int c = 0; c < 4; ++c)
        xs_t[w * 32 + j * 4 + c][tok] = v[c];
    }
  }
  __syncthreads();

  // L1: 128 -> 32; wave w owns outputs w*8 .. w*8+7
  const float* __restrict__ W1u = wr11 + e12 * 4096 + w * 8;
  const float* __restrict__ B1u = br11 + e12 * 32 + w * 8;
  float a[8];
#pragma unroll
  for (int o = 0; o < 8; ++o) a[o] = B1u[o];
#pragma unroll 8
  for (int k = 0; k < 128; ++k) {
    const float xv = xs_t[k][tok];
#pragma unroll
    for (int o = 0; o < 8; ++o)
      a[o] = fmaf(xv, W1u[k * 32 + o], a[o]);
  }
#pragma unroll
  for (int o = 0; o < 8; ++o) {
    const float v = a[o] > 0.f ? a[o] : 0.01f * a[o];
    actA[w * 8 + o][tok] = v;
  }
  __syncthreads();

  // L2: 32 -> 16; wave w owns outputs w*4 .. w*4+3
  const float* __restrict__ W2u = wr12 + e12 * 512 + w * 4;
  const float* __restrict__ B2u = br12 + e12 * 16 + w * 4;
  float s[4];
#pragma unroll
  for (int j = 0; j < 4; ++j) s[j] = B2u[j];
#pragma unroll 8
  for (int i = 0; i < 32; ++i) {
    const float hv = actA[i][tok];
#pragma unroll
    for (int j = 0; j < 4; ++j)
      s[j] = fmaf(hv, W2u[i * 16 + j], s[j]);
  }
#pragma unroll
  for (int j = 0; j < 4; ++j) {
    const float v = s[j] > 0.f ? s[j] : 0.01f * s[j];
    actB[w * 4 + j][tok] = v;
  }
  __syncthreads();

  // L3: 16 -> 1 (i ascending, scalar weights); lane = token
  if (t < 64) {
    float r = br13[e12];
    const float* __restrict__ W3u = wr13 + e12 * 16;
#pragma unroll
    for (int i = 0; i < 16; ++i)
      r = fmaf(actB[i][tok], W3u[i], r);
    if (valid) out[n] = ((float)e12 + r) * (1.0f / 256.0f);
  }
}

// ---------------------------------------------------------------------------
extern "C" void kernel_launch(void* const* d_in, const int* in_sizes, int n_in,
                              void* d_out, int out_size, void* d_ws,
                              size_t ws_size, hipStream_t stream) {
  const float* x_in  = (const float*)d_in[0];
  const float* w_c11 = (const float*)d_in[1];
  const float* b_c11 = (const float*)d_in[2];
  const float* w_c12 = (const float*)d_in[3];
  const float* b_c12 = (const float*)d_in[4];
  const float* w_c13 = (const float*)d_in[5];
  const float* b_c13 = (const float*)d_in[6];
  const float* w_c21 = (const float*)d_in[7];
  const float* b_c21 = (const float*)d_in[8];
  const float* w_c22 = (const float*)d_in[9];
  const float* b_c22 = (const float*)d_in[10];
  const float* w_c23 = (const float*)d_in[11];
  const float* b_c23 = (const float*)d_in[12];
  const float* w_r11 = (const float*)d_in[13];
  const float* b_r11 = (const float*)d_in[14];
  const float* w_r12 = (const float*)d_in[15];
  const float* b_r12 = (const float*)d_in[16];
  const float* w_r13 = (const float*)d_in[17];
  const float* b_r13 = (const float*)d_in[18];

  float* out = (float*)d_out;   // [0..N): x_real (token order), [N..2N): mask

  float* R0 = (float*)d_ws;
  float* R1 = R0 + 128 * NPIX;
  float* R2 = R1 + 128 * NPIX;

  float* xt = R0;
  unsigned char* inds1 = (unsigned char*)R2;   // N bytes
  float* wT1 = R2 + 12288;
  float* wT2 = wT1 + 16384;
  int* S = (int*)R2 + 45056;

  int* cnt1  = S;            // 16
  int* cur1  = S + 16;       // 16
  int* off1  = S + 32;       // 16
  int* nd1   = S + 48;       // 1 (+pad)
  int* desc1 = S + 64;       // 1024
  int* cnt2  = S + 1088;     // 256
  int* cur2  = S + 1344;     // 256
  int* off2  = S + 1600;     // 256
  int* nd2   = S + 1856;     // 1 (+pad)
  int* desc2 = S + 1872;     // 1024

  int* ib   = (int*)R1;
  int* ord1 = ib;            // N
  int* ord2 = ib + NPIX;     // N
  int* e12a = ib + 2 * NPIX; // N

  wtrans2_k<<<32, 256, 0, stream>>>(w_c11, wT1, w_c12, wT2, S);
  convfused_k<<<NPIX / 64, 512, 0, stream>>>(x_in, wT1, b_c11, wT2, b_c12,
      w_c13, b_c13, inds1, out + NPIX, cnt1, xt);
  scan_desc_k<16><<<1, 256, 0, stream>>>(cnt1, off1, desc1, nd1);
  scatter_k<unsigned char><<<NPIX / 256, 256, 0, stream>>>(inds1, off1, cur1,
                                                           ord1, 16);
  chain1_k<<<NPIX / TPB + 16, 256, 0, stream>>>(xt, ord1, off1, cnt1, desc1,
      nd1, w_c21, b_c21, w_c22, b_c22, w_c23, b_c23, e12a, cnt2);
  scan_desc_k<256><<<1, 256, 0, stream>>>(cnt2, off2, desc2, nd2);
  scatter_k<int><<<NPIX / 256, 256, 0, stream>>>(e12a, off2, cur2, ord2, 256);
  chain2_k<<<NPIX / TPB + 256, 256, 0, stream>>>(xt, ord2, off2, cnt2, desc2,
      nd2, w_r11, b_r11, w_r12, b_r12, w_r13, b_r13, out);
}

// Round 16
// 114.930 us; speedup vs baseline: 1.2718x; 1.2564x over previous
//
#include <hip/hip_runtime.h>

#define NPIX 49152   // B*H*W = 1*192*256
#define H_ 192
#define W_ 256
#define TPB 64       // tokens per chain block (64 tokens; 256 thr = 4 waves)

// ---------------------------------------------------------------------------
// both weight transposes (32 blocks) + zero binning counters (block 0)
// ---------------------------------------------------------------------------
__global__ __launch_bounds__(256) void wtrans2_k(const float* __restrict__ Wa,
    float* __restrict__ WTa, const float* __restrict__ Wb,
    float* __restrict__ WTb, int* __restrict__ S) {
  const int b = blockIdx.x;
  const float* __restrict__ W = (b < 16) ? Wa : Wb;
  float* __restrict__ WT = (b < 16) ? WTa : WTb;
  const int bb = b & 15;
  __shared__ float tile[32][33];
  const int bx = bb & 3, by = bb >> 2;
  const int c = threadIdx.x & 31, r0 = threadIdx.x >> 5;
#pragma unroll
  for (int j = 0; j < 4; ++j) {
    const int r = r0 + j * 8;
    tile[r][c] = W[(by * 32 + r) * 128 + bx * 32 + c];
  }
  __syncthreads();
#pragma unroll
  for (int j = 0; j < 4; ++j) {
    const int r = r0 + j * 8;
    WT[(bx * 32 + r) * 128 + by * 32 + c] = tile[c][r];
  }
  if (b == 0) {
    const int t = threadIdx.x;
    if (t < 32) S[t] = 0;        // cnt1 + cur1
    S[1088 + t] = 0;             // cnt2
    S[1344 + t] = 0;             // cur2
  }
}

// ---------------------------------------------------------------------------
// FUSED conv1 + conv2 + conv17 + argmax + mask + histogram + x transpose.
// (round-13 version, proven ~58 µs: 512 thr, 16 outputs/wave, scalar weights
//  — scalar path pays here because ALL blocks share the same weight matrices)
// ---------------------------------------------------------------------------
__global__ __launch_bounds__(512) void convfused_k(const float* __restrict__ X,
    const float* __restrict__ WT1, const float* __restrict__ Bv1,
    const float* __restrict__ WT2, const float* __restrict__ Bv2,
    const float* __restrict__ W3, const float* __restrict__ Bv3,
    unsigned char* __restrict__ inds1, float* __restrict__ mask_out,
    int* __restrict__ cnt1, float* __restrict__ xt) {
  __shared__ float xs2[128][65];   // 33.3 KB raw x, then activations (pad 65)
  __shared__ float w3s[128 * 20];  // 10 KB W3 [k][20]
  __shared__ int lh[16];
  const int t = threadIdx.x;
  const int px = t & 63;           // lane = pixel within tile
  const int p0 = blockIdx.x * 64;
  int ob = (t >> 6) * 16;          // wave's 16-output base == its k-row base
  ob = __builtin_amdgcn_readfirstlane(ob);
  if (t < 16) lh[t] = 0;

  // ---- stage raw x: wave w loads k rows [ob, ob+16) for all 64 px ----
  {
    float xr[16];
#pragma unroll
    for (int kk = 0; kk < 16; ++kk)
      xr[kk] = X[(ob + kk) * NPIX + p0 + px];
#pragma unroll
    for (int kk = 0; kk < 16; ++kk)
      xs2[ob + kk][px] = xr[kk];
  }
  __syncthreads();

  float acc[16];

  // ================= PHASE 1: conv1 (x from LDS, W scalar) ===============
  const float* __restrict__ W1u = WT1 + ob;   // uniform base
#pragma unroll
  for (int o = 0; o < 16; ++o) acc[o] = Bv1[ob + o];
#pragma unroll 8
  for (int k = 0; k < 128; ++k) {
    const float xv = xs2[k][px];
#pragma unroll
    for (int o = 0; o < 16; ++o)
      acc[o] = fmaf(xv, W1u[k * 128 + o], acc[o]);
  }

  // ---- xt transpose write (coalesced row bursts from LDS cols) ----
#pragma unroll
  for (int i = 0; i < 4; ++i) {
    const int idx = t * 4 + i;
    const int tok = idx >> 5, c4 = idx & 31;   // token 0..63, f4-col 0..31
    const int pg = p0 + tok;
    float4 v;
    v.x = xs2[c4 * 4 + 0][tok];
    v.y = xs2[c4 * 4 + 1][tok];
    v.z = xs2[c4 * 4 + 2][tok];
    v.w = xs2[c4 * 4 + 3][tok];
    *(float4*)(xt + ((pg & 255) * H_ + (pg >> 8)) * 128 + c4 * 4) = v;
  }
  __syncthreads();   // xt LDS reads + phase-1 reads done before overwrite

  // epilogue 1: lrelu -> xs2 (activations)
#pragma unroll
  for (int o = 0; o < 16; ++o) {
    const float v = acc[o];
    xs2[ob + o][px] = v > 0.f ? v : 0.01f * v;
  }
  __syncthreads();

  // ================= PHASE 2: conv2 (x from LDS, W scalar) ===============
  const float* __restrict__ W2u = WT2 + ob;
#pragma unroll
  for (int o = 0; o < 16; ++o) acc[o] = Bv2[ob + o];
#pragma unroll 8
  for (int k = 0; k < 128; ++k) {
    const float xv = xs2[k][px];
#pragma unroll
    for (int o = 0; o < 16; ++o)
      acc[o] = fmaf(xv, W2u[k * 128 + o], acc[o]);
  }
  __syncthreads();   // all phase-2 reads of xs2 complete

  // epilogue 2: lrelu -> xs2 ; stage W3 as w3s[k][20]
#pragma unroll
  for (int o = 0; o < 16; ++o) {
    const float v = acc[o];
    xs2[ob + o][px] = v > 0.f ? v : 0.01f * v;
  }
  for (int i = t; i < 17 * 128; i += 512)
    w3s[(i & 127) * 20 + (i >> 7)] = W3[i];
  __syncthreads();

  // ===== PHASE 3: conv17 + argmax + mask + hist (8 lanes per pixel) =====
  {
    const int p = t >> 3, s = t & 7;      // pixel 0..63, logit-pair owner
    float s2[2];
    s2[0] = Bv3[2 * s];
    s2[1] = Bv3[2 * s + 1];
    float m = Bv3[16];
#pragma unroll 8
    for (int k = 0; k < 128; ++k) {
      const float xv = xs2[k][p];
      float2 w2 = *(const float2*)&w3s[k * 20 + 2 * s];
      s2[0] = fmaf(xv, w2.x, s2[0]);
      s2[1] = fmaf(xv, w2.y, s2[1]);
      m = fmaf(xv, w3s[k * 20 + 16], m);
    }
    float bv = s2[0];
    int bi = 2 * s;
    if (s2[1] > bv) { bv = s2[1]; bi = 2 * s + 1; }
#pragma unroll
    for (int d = 1; d < 8; d <<= 1) {
      const float ov = __shfl_xor(bv, d, 64);
      const int oi = __shfl_xor(bi, d, 64);
      if (ov > bv || (ov == bv && oi < bi)) { bv = ov; bi = oi; }
    }
    if (s == 0) {
      inds1[p0 + p] = (unsigned char)bi;
      mask_out[p0 + p] = m > 0.f ? m : 0.01f * m;
      atomicAdd(&lh[bi], 1);
    }
  }
  __syncthreads();
  if (t < 16 && lh[t] > 0) atomicAdd(&cnt1[t], lh[t]);
}

// ---------------------------------------------------------------------------
// two-level scatter; bin offsets computed in-block from cnt (shfl scan) —
// identical arithmetic to the old scan_desc_k, dispatch eliminated.
// ---------------------------------------------------------------------------
template<typename T>
__global__ __launch_bounds__(256) void scatter_k(const T* __restrict__ bins,
    const int* __restrict__ cnt, int* __restrict__ cursor,
    int* __restrict__ ord, int nbins) {
  __shared__ int loff[256], lhist[256], lbase[256], lcur[256];
  __shared__ int wsC[4];
  const int t = threadIdx.x;
  const int lane = t & 63, wvi = t >> 6;
  const int c = (t < nbins) ? cnt[t] : 0;
  int ic = c;
  for (int d = 1; d < 64; d <<= 1) {
    const int u = __shfl_up(ic, d, 64);
    if (lane >= d) ic += u;
  }
  if (lane == 63) wsC[wvi] = ic;
  if (t < nbins) { lhist[t] = 0; lcur[t] = 0; }
  __syncthreads();
  int bc = 0;
#pragma unroll
  for (int w2 = 0; w2 < 4; ++w2) if (w2 < wvi) bc += wsC[w2];
  ic += bc;
  if (t < nbins) loff[t] = ic - c;
  __syncthreads();
  const int n = blockIdx.x * 256 + t;
  const int b = (int)bins[n];
  atomicAdd(&lhist[b], 1);
  __syncthreads();
  if (t < nbins && lhist[t] > 0) lbase[t] = atomicAdd(&cursor[t], lhist[t]);
  __syncthreads();
  const int r = atomicAdd(&lcur[b], 1);
  ord[loff[b] + lbase[b] + r] = n;
}

// ---------------------------------------------------------------------------
// chain1 v5 (reverted): LDS-staged expert weights + x rows; pure-LDS k-loop.
// Descriptor (e, chunk, off, cnt) derived in-block from cnt1 via shfl scan.
// ---------------------------------------------------------------------------
__global__ __launch_bounds__(256) void chain1_k(const float* __restrict__ xt,
    const int* __restrict__ ord1, const int* __restrict__ cnt1,
    const float* __restrict__ wc21, const float* __restrict__ bc21,
    const float* __restrict__ wc22, const float* __restrict__ bc22,
    const float* __restrict__ wc23, const float* __restrict__ bc23,
    int* __restrict__ e12a, int* __restrict__ cnt2) {
  __shared__ float w1s[4096];
  __shared__ float w2s[1024];
  __shared__ float w3s[512];
  __shared__ float bs[80];
  __shared__ float xs_[64][132];
  __shared__ int lh[16];
  __shared__ int sel[4];
  __shared__ int wsC[4], wsD[4];
  const int t = threadIdx.x;
  const int lane = t & 63, wvi = t >> 6;
  if (t == 0) sel[0] = -1;
  if (t < 16) lh[t] = 0;
  // descriptor scan over 16 bins
  {
    const int cb = (t < 16) ? cnt1[t] : 0;
    const int nb = (cb + TPB - 1) / TPB;
    int ic = cb, id = nb;
    for (int d = 1; d < 64; d <<= 1) {
      const int uc = __shfl_up(ic, d, 64);
      const int ud = __shfl_up(id, d, 64);
      if (lane >= d) { ic += uc; id += ud; }
    }
    if (lane == 63) { wsC[wvi] = ic; wsD[wvi] = id; }
    __syncthreads();
    int bc = 0, bd = 0;
#pragma unroll
    for (int w2 = 0; w2 < 4; ++w2) {
      if (w2 < wvi) { bc += wsC[w2]; bd += wsD[w2]; }
    }
    ic += bc; id += bd;
    const int accB = id - nb, accO = ic - cb;
    if (t < 16 && (int)blockIdx.x >= accB && (int)blockIdx.x < accB + nb) {
      sel[0] = t; sel[1] = blockIdx.x - accB; sel[2] = accO; sel[3] = cb;
    }
  }
  __syncthreads();
  if (sel[0] < 0) return;
  const int e     = __builtin_amdgcn_readfirstlane(sel[0]);
  const int chunk = __builtin_amdgcn_readfirstlane(sel[1]);
  const int offe  = __builtin_amdgcn_readfirstlane(sel[2]);
  const int cnt   = __builtin_amdgcn_readfirstlane(sel[3]);

  const int tg = t >> 2, sub = t & 3;
  const int l0 = (t & 63) & ~3;
  const int pos = chunk * TPB + tg;
  const bool valid = pos < cnt;
  const int n = valid ? ord1[offe + pos] : 0;

  {
    const float4* __restrict__ Wg1 = (const float4*)(wc21 + e * 4096);
#pragma unroll
    for (int j = 0; j < 4; ++j)
      *(float4*)&w1s[t * 4 + j * 1024] = Wg1[t + j * 256];
    const float4* __restrict__ Wg2 = (const float4*)(wc22 + e * 1024);
    *(float4*)&w2s[t * 4] = Wg2[t];
    if (t < 128) {
      const float4* __restrict__ Wg3 = (const float4*)(wc23 + e * 512);
      *(float4*)&w3s[t * 4] = Wg3[t];
    }
    if (t < 32) bs[t] = bc21[e * 32 + t];
    else if (t < 64) bs[t] = bc22[e * 32 + (t - 32)];
    else if (t < 80) bs[t] = bc23[e * 16 + (t - 64)];
  }
  {
    const float4* __restrict__ src = (const float4*)(xt + n * 128 + sub * 32);
    float4 tmp[8];
#pragma unroll
    for (int j = 0; j < 8; ++j) tmp[j] = src[j];
#pragma unroll
    for (int j = 0; j < 8; ++j)
      *(float4*)(&xs_[tg][sub * 32 + 4 * j]) = tmp[j];
  }
  __syncthreads();

  const int wb1 = sub * 8;
  float a[8];
#pragma unroll
  for (int o = 0; o < 8; ++o) a[o] = bs[wb1 + o];
#pragma unroll
  for (int k = 0; k < 128; k += 4) {
    float x4[4];
    *(float4*)x4 = *(const float4*)(&xs_[tg][k]);
#pragma unroll
    for (int kk = 0; kk < 4; ++kk) {
      float w8[8];
      *(float4*)&w8[0] = *(const float4*)&w1s[(k + kk) * 32 + wb1];
      *(float4*)&w8[4] = *(const float4*)&w1s[(k + kk) * 32 + wb1 + 4];
#pragma unroll
      for (int o = 0; o < 8; ++o) a[o] = fmaf(x4[kk], w8[o], a[o]);
    }
  }
#pragma unroll
  for (int o = 0; o < 8; ++o) a[o] = a[o] > 0.f ? a[o] : 0.01f * a[o];

  float b[8];
#pragma unroll
  for (int o = 0; o < 8; ++o) b[o] = bs[32 + wb1 + o];
#pragma unroll
  for (int i = 0; i < 32; ++i) {
    const float hv = __shfl(a[i & 7], l0 + (i >> 3), 64);
    float w8[8];
    *(float4*)&w8[0] = *(const float4*)&w2s[i * 32 + wb1];
    *(float4*)&w8[4] = *(const float4*)&w2s[i * 32 + wb1 + 4];
#pragma unroll
    for (int o = 0; o < 8; ++o) b[o] = fmaf(hv, w8[o], b[o]);
  }
#pragma unroll
  for (int o = 0; o < 8; ++o) b[o] = b[o] > 0.f ? b[o] : 0.01f * b[o];

  float s[4];
#pragma unroll
  for (int j = 0; j < 4; ++j) s[j] = bs[64 + sub * 4 + j];
#pragma unroll
  for (int i = 0; i < 32; ++i) {
    const float hv = __shfl(b[i & 7], l0 + (i >> 3), 64);
    float w4[4];
    *(float4*)w4 = *(const float4*)&w3s[i * 16 + sub * 4];
#pragma unroll
    for (int j = 0; j < 4; ++j) s[j] = fmaf(hv, w4[j], s[j]);
  }

  float bv = s[0];
  int bi = sub * 4;
#pragma unroll
  for (int j = 1; j < 4; ++j) {
    if (s[j] > bv) { bv = s[j]; bi = sub * 4 + j; }
  }
#pragma unroll
  for (int d = 1; d < 4; d <<= 1) {
    const float ov = __shfl_xor(bv, d, 64);
    const int oi = __shfl_xor(bi, d, 64);
    if (ov > bv || (ov == bv && oi < bi)) { bv = ov; bi = oi; }
  }
  const int e12 = e * 16 + bi;
  if (valid && sub == 0) {
    e12a[n] = e12;
    atomicAdd(&lh[bi], 1);
  }
  __syncthreads();
  if (t < 16 && lh[t] > 0)
    atomicAdd(&cnt2[e * 16 + t], lh[t]);
}

// ---------------------------------------------------------------------------
// chain2 v5 (reverted): LDS-weight-staged; descriptor from cnt2 (256 bins).
// ---------------------------------------------------------------------------
__global__ __launch_bounds__(256) void chain2_k(const float* __restrict__ xt,
    const int* __restrict__ ord2, const int* __restrict__ cnt2,
    const float* __restrict__ wr11, const float* __restrict__ br11,
    const float* __restrict__ wr12, const float* __restrict__ br12,
    const float* __restrict__ wr13, const float* __restrict__ br13,
    float* __restrict__ out) {
  __shared__ float w1s[4096];
  __shared__ float w2s[512];
  __shared__ float w3s[16];
  __shared__ float bs[49];
  __shared__ float xs_[64][132];
  __shared__ int sel[4];
  __shared__ int wsC[4], wsD[4];
  const int t = threadIdx.x;
  const int lane = t & 63, wvi = t >> 6;
  if (t == 0) sel[0] = -1;
  // descriptor scan over 256 bins
  {
    const int cb = cnt2[t];
    const int nb = (cb + TPB - 1) / TPB;
    int ic = cb, id = nb;
    for (int d = 1; d < 64; d <<= 1) {
      const int uc = __shfl_up(ic, d, 64);
      const int ud = __shfl_up(id, d, 64);
      if (lane >= d) { ic += uc; id += ud; }
    }
    if (lane == 63) { wsC[wvi] = ic; wsD[wvi] = id; }
    __syncthreads();
    int bc = 0, bd = 0;
#pragma unroll
    for (int w2 = 0; w2 < 4; ++w2) {
      if (w2 < wvi) { bc += wsC[w2]; bd += wsD[w2]; }
    }
    ic += bc; id += bd;
    const int accB = id - nb, accO = ic - cb;
    if ((int)blockIdx.x >= accB && (int)blockIdx.x < accB + nb) {
      sel[0] = t; sel[1] = blockIdx.x - accB; sel[2] = accO; sel[3] = cb;
    }
  }
  __syncthreads();
  if (sel[0] < 0) return;
  const int e12   = __builtin_amdgcn_readfirstlane(sel[0]);
  const int chunk = __builtin_amdgcn_readfirstlane(sel[1]);
  const int offe  = __builtin_amdgcn_readfirstlane(sel[2]);
  const int cnt   = __builtin_amdgcn_readfirstlane(sel[3]);

  const int tg = t >> 2, sub = t & 3;
  const int l0 = (t & 63) & ~3;
  const int pos = chunk * TPB + tg;
  const bool valid = pos < cnt;
  const int n = valid ? ord2[offe + pos] : 0;

  {
    const float4* __restrict__ Wg1 = (const float4*)(wr11 + e12 * 4096);
#pragma unroll
    for (int j = 0; j < 4; ++j)
      *(float4*)&w1s[t * 4 + j * 1024] = Wg1[t + j * 256];
    if (t < 128) {
      const float4* __restrict__ Wg2 = (const float4*)(wr12 + e12 * 512);
      *(float4*)&w2s[t * 4] = Wg2[t];
    }
    if (t < 16) w3s[t] = wr13[e12 * 16 + t];
    if (t < 32) bs[t] = br11[e12 * 32 + t];
    else if (t < 48) bs[t] = br12[e12 * 16 + (t - 32)];
    else if (t == 48) bs[48] = br13[e12];
  }
  {
    const float4* __restrict__ src = (const float4*)(xt + n * 128 + sub * 32);
    float4 tmp[8];
#pragma unroll
    for (int j = 0; j < 8; ++j) tmp[j] = src[j];
#pragma unroll
    for (int j = 0; j < 8; ++j)
      *(float4*)(&xs_[tg][sub * 32 + 4 * j]) = tmp[j];
  }
  __syncthreads();

  const int wb1 = sub * 8;
  float a[8];
#pragma unroll
  for (int o = 0; o < 8; ++o) a[o] = bs[wb1 + o];
#pragma unroll
  for (int k = 0; k < 128; k += 4) {
    float x4[4];
    *(float4*)x4 = *(const float4*)(&xs_[tg][k]);
#pragma unroll
    for (int kk = 0; kk < 4; ++kk) {
      float w8[8];
      *(float4*)&w8[0] = *(const float4*)&w1s[(k + kk) * 32 + wb1];
      *(float4*)&w8[4] = *(const float4*)&w1s[(k + kk) * 32 + wb1 + 4];
#pragma unroll
      for (int o = 0; o < 8; ++o) a[o] = fmaf(x4[kk], w8[o], a[o]);
    }
  }
#pragma unroll
  for (int o = 0; o < 8; ++o) a[o] = a[o] > 0.f ? a[o] : 0.01f * a[o];

  float s[4];
#pragma unroll
  for (int j = 0; j < 4; ++j) s[j] = bs[32 + sub * 4 + j];
#pragma unroll
  for (int i = 0; i < 32; ++i) {
    const float hv = __shfl(a[i & 7], l0 + (i >> 3), 64);
    float w4[4];
    *(float4*)w4 = *(const float4*)&w2s[i * 16 + sub * 4];
#pragma unroll
    for (int j = 0; j < 4; ++j) s[j] = fmaf(hv, w4[j], s[j]);
  }
#pragma unroll
  for (int j = 0; j < 4; ++j) s[j] = s[j] > 0.f ? s[j] : 0.01f * s[j];

  float r = bs[48];
#pragma unroll
  for (int i = 0; i < 16; ++i) {
    const float hv = __shfl(s[i & 3], l0 + (i >> 2), 64);
    r = fmaf(hv, w3s[i], r);
  }

  if (valid && sub == 0) out[n] = ((float)e12 + r) * (1.0f / 256.0f);
}

// ---------------------------------------------------------------------------
extern "C" void kernel_launch(void* const* d_in, const int* in_sizes, int n_in,
                              void* d_out, int out_size, void* d_ws,
                              size_t ws_size, hipStream_t stream) {
  const float* x_in  = (const float*)d_in[0];
  const float* w_c11 = (const float*)d_in[1];
  const float* b_c11 = (const float*)d_in[2];
  const float* w_c12 = (const float*)d_in[3];
  const float* b_c12 = (const float*)d_in[4];
  const float* w_c13 = (const float*)d_in[5];
  const float* b_c13 = (const float*)d_in[6];
  const float* w_c21 = (const float*)d_in[7];
  const float* b_c21 = (const float*)d_in[8];
  const float* w_c22 = (const float*)d_in[9];
  const float* b_c22 = (const float*)d_in[10];
  const float* w_c23 = (const float*)d_in[11];
  const float* b_c23 = (const float*)d_in[12];
  const float* w_r11 = (const float*)d_in[13];
  const float* b_r11 = (const float*)d_in[14];
  const float* w_r12 = (const float*)d_in[15];
  const float* b_r12 = (const float*)d_in[16];
  const float* w_r13 = (const float*)d_in[17];
  const float* b_r13 = (const float*)d_in[18];

  float* out = (float*)d_out;   // [0..N): x_real (token order), [N..2N): mask

  float* R0 = (float*)d_ws;
  float* R1 = R0 + 128 * NPIX;
  float* R2 = R1 + 128 * NPIX;

  float* xt = R0;
  unsigned char* inds1 = (unsigned char*)R2;   // N bytes
  float* wT1 = R2 + 12288;
  float* wT2 = wT1 + 16384;
  int* S = (int*)R2 + 45056;

  int* cnt1 = S;             // 16
  int* cur1 = S + 16;        // 16
  int* cnt2 = S + 1088;      // 256
  int* cur2 = S + 1344;      // 256

  int* ib   = (int*)R1;
  int* ord1 = ib;            // N
  int* ord2 = ib + NPIX;     // N
  int* e12a = ib + 2 * NPIX; // N

  wtrans2_k<<<32, 256, 0, stream>>>(w_c11, wT1, w_c12, wT2, S);
  convfused_k<<<NPIX / 64, 512, 0, stream>>>(x_in, wT1, b_c11, wT2, b_c12,
      w_c13, b_c13, inds1, out + NPIX, cnt1, xt);
  scatter_k<unsigned char><<<NPIX / 256, 256, 0, stream>>>(inds1, cnt1, cur1,
                                                           ord1, 16);
  chain1_k<<<NPIX / TPB + 16, 256, 0, stream>>>(xt, ord1, cnt1,
      w_c21, b_c21, w_c22, b_c22, w_c23, b_c23, e12a, cnt2);
  scatter_k<int><<<NPIX / 256, 256, 0, stream>>>(e12a, cnt2, cur2, ord2, 256);
  chain2_k<<<NPIX / TPB + 256, 256, 0, stream>>>(xt, ord2, cnt2,
      w_r11, b_r11, w_r12, b_r12, w_r13, b_r13, out);
}